// Round 1
// baseline (493.951 us; speedup 1.0000x reference)
//
#include <hip/hip_runtime.h>
#include <hip/hip_bf16.h>
#include <math.h>

#define NROWS 8192
#define DIM   2048
#define NC    256
#define ALPHA_C 7.18f

typedef float  f32x4  __attribute__((ext_vector_type(4)));
typedef __bf16 bf16x8 __attribute__((ext_vector_type(8)));

// ---------------- workspace layout (bytes) ----------------
// A_swz : 32 MiB  bf16 [512 mt][64 kk][64 lane][8]
// dot   :  8 MiB  f32  [8192][256]
// ps    :  4 MiB  f32  partial segment sums [2][256][2048]
// B_swz :  1 MiB  bf16 [16 nt][64 kk][64 lane][8]
// counts:  1 KiB  f32[256]
// mnorm2:  1 KiB  f32[256]
// onorm2: 32 KiB  f32[8192]
// scal  :  64 B   [0]=sum_resid(atomic) [1]=num_instances [2]=stdev [3]=loss_sum(atomic)
#define OFF_A      (size_t)0
#define OFF_DOT    ((size_t)32 << 20)
#define OFF_PS     ((size_t)40 << 20)
#define OFF_B      ((size_t)44 << 20)
#define OFF_CNT    ((size_t)45 << 20)
#define OFF_MN2    (OFF_CNT + 1024)
#define OFF_ON2    (OFF_CNT + 2048)
#define OFF_SCAL   (OFF_CNT + 2048 + 32768)

__device__ __forceinline__ float wave_red_sum(float v) {
#pragma unroll
  for (int off = 32; off > 0; off >>= 1) v += __shfl_xor(v, off, 64);
  return v;
}

// ---------------- counts + num_instances ----------------
__global__ __launch_bounds__(256) void k_counts(const int* __restrict__ clu,
                                                float* __restrict__ counts,
                                                float* scal) {
  __shared__ int cnt[NC];
  __shared__ float part[4];
  int tid = threadIdx.x;
  cnt[tid] = 0;
  __syncthreads();
  for (int i = tid; i < NROWS; i += 256) atomicAdd(&cnt[clu[i]], 1);
  __syncthreads();
  int c = cnt[tid];
  counts[tid] = (float)c;
  float v = (c >= 4) ? (float)c : 0.0f;
  v = wave_red_sum(v);
  if ((tid & 63) == 0) part[tid >> 6] = v;
  __syncthreads();
  if (tid == 0) scal[1] = part[0] + part[1] + part[2] + part[3];
}

// ---------------- segment sums (column-sliced, LDS accumulate) ----------------
// grid 128 = 64 column-groups x 2 row-halves; block owns cols [32cg,32cg+32)
__global__ __launch_bounds__(256) void k_sums(const float* __restrict__ out,
                                              const int* __restrict__ clu,
                                              float* __restrict__ ps) {
  __shared__ float lsum[NC * 32];
  int bid = blockIdx.x;
  int cg = bid >> 1, rg = bid & 1;
  int tid = threadIdx.x;
  for (int i = tid; i < NC * 32; i += 256) lsum[i] = 0.f;
  __syncthreads();
  int col = tid & 31, rs = tid >> 5;
  const float* src = out + (size_t)rg * 4096 * DIM + cg * 32 + col;
  const int* cl = clu + rg * 4096;
  for (int r = rs; r < 4096; r += 8) {
    int c = cl[r];
    float v = src[(size_t)r * DIM];
    atomicAdd(&lsum[c * 32 + col], v);
  }
  __syncthreads();
  float* dst = ps + (size_t)rg * NC * DIM + (size_t)cg * 32;
  for (int i = tid; i < NC * 32; i += 256) {
    int c = i >> 5, c2 = i & 31;
    dst[(size_t)c * DIM + c2] = lsum[i];
  }
}

// ---------------- convert outputs -> A_swz (bf16 fragment layout) + onorm2 ----------------
// one block per row
__global__ __launch_bounds__(256) void k_conv(const float* __restrict__ out,
                                              bf16x8* __restrict__ A,
                                              float* __restrict__ onorm2) {
  __shared__ float part[4];
  int r = blockIdx.x, tid = threadIdx.x;
  const f32x4* src = (const f32x4*)(out + (size_t)r * DIM);
  f32x4 v0 = src[tid * 2], v1 = src[tid * 2 + 1];
  float s = 0.f;
  bf16x8 b;
#pragma unroll
  for (int j = 0; j < 4; ++j) { float f = v0[j]; s += f * f; b[j] = (__bf16)f; }
#pragma unroll
  for (int j = 0; j < 4; ++j) { float f = v1[j]; s += f * f; b[4 + j] = (__bf16)f; }
  int mt = r >> 4, kk = tid >> 2, lane = (tid & 3) * 16 + (r & 15);
  A[((size_t)mt * 64 + kk) * 64 + lane] = b;
  s = wave_red_sum(s);
  if ((tid & 63) == 0) part[tid >> 6] = s;
  __syncthreads();
  if (tid == 0) onorm2[r] = part[0] + part[1] + part[2] + part[3];
}

// ---------------- means -> B_swz (bf16 fragment layout) + mnorm2 ----------------
// one block per cluster
__global__ __launch_bounds__(256) void k_means(const float* __restrict__ ps,
                                               const float* __restrict__ counts,
                                               bf16x8* __restrict__ B,
                                               float* __restrict__ mnorm2) {
  __shared__ float part[4];
  int c = blockIdx.x, tid = threadIdx.x;
  int d0 = tid * 8;
  const f32x4* p0 = (const f32x4*)(ps + (size_t)c * DIM + d0);
  const f32x4* p1 = (const f32x4*)(ps + (size_t)(NC + c) * DIM + d0);
  f32x4 a0 = p0[0], a1 = p0[1], c0 = p1[0], c1 = p1[1];
  float inv = 1.0f / fmaxf(counts[c], 1.0f);
  bf16x8 m;
  float s = 0.f;
#pragma unroll
  for (int j = 0; j < 4; ++j) { float mj = (a0[j] + c0[j]) * inv; s += mj * mj; m[j] = (__bf16)mj; }
#pragma unroll
  for (int j = 0; j < 4; ++j) { float mj = (a1[j] + c1[j]) * inv; s += mj * mj; m[4 + j] = (__bf16)mj; }
  int nt = c >> 4, kk = tid >> 2, lane = (tid & 3) * 16 + (c & 15);
  B[((size_t)nt * 64 + kk) * 64 + lane] = m;
  s = wave_red_sum(s);
  if ((tid & 63) == 0) part[tid >> 6] = s;
  __syncthreads();
  if (tid == 0) mnorm2[c] = part[0] + part[1] + part[2] + part[3];
}

// ---------------- GEMM: dot[i][c] = outputs_i . mean_c (bf16 MFMA) ----------------
// 256 blocks = 64 M-blocks x 4 N-blocks (XCD-swizzled); 4 waves, wave = 32x64 output
__global__ __launch_bounds__(256) void k_gemm(const bf16x8* __restrict__ A,
                                              const bf16x8* __restrict__ B,
                                              float* __restrict__ dot) {
  int bid = blockIdx.x;
  int wg = (bid & 7) * 32 + (bid >> 3);   // bijective: 256 = 8 XCD x 32
  int bm = wg >> 2, bn = wg & 3;
  int w = threadIdx.x >> 6, l = threadIdx.x & 63;
  int mt0 = bm * 8 + w * 2;
  int nt0 = bn * 4;
  const bf16x8* Ap = A + (size_t)mt0 * 64 * 64 + l;
  const bf16x8* Bp = B + (size_t)nt0 * 64 * 64 + l;
  f32x4 acc[2][4] = {};
  for (int kk = 0; kk < 64; ++kk) {
    bf16x8 a0 = Ap[kk * 64];
    bf16x8 a1 = Ap[4096 + kk * 64];
    bf16x8 b0 = Bp[kk * 64];
    bf16x8 b1 = Bp[4096 + kk * 64];
    bf16x8 b2 = Bp[8192 + kk * 64];
    bf16x8 b3 = Bp[12288 + kk * 64];
    acc[0][0] = __builtin_amdgcn_mfma_f32_16x16x32_bf16(a0, b0, acc[0][0], 0, 0, 0);
    acc[0][1] = __builtin_amdgcn_mfma_f32_16x16x32_bf16(a0, b1, acc[0][1], 0, 0, 0);
    acc[0][2] = __builtin_amdgcn_mfma_f32_16x16x32_bf16(a0, b2, acc[0][2], 0, 0, 0);
    acc[0][3] = __builtin_amdgcn_mfma_f32_16x16x32_bf16(a0, b3, acc[0][3], 0, 0, 0);
    acc[1][0] = __builtin_amdgcn_mfma_f32_16x16x32_bf16(a1, b0, acc[1][0], 0, 0, 0);
    acc[1][1] = __builtin_amdgcn_mfma_f32_16x16x32_bf16(a1, b1, acc[1][1], 0, 0, 0);
    acc[1][2] = __builtin_amdgcn_mfma_f32_16x16x32_bf16(a1, b2, acc[1][2], 0, 0, 0);
    acc[1][3] = __builtin_amdgcn_mfma_f32_16x16x32_bf16(a1, b3, acc[1][3], 0, 0, 0);
  }
  // C/D layout (m89-verified): col = l&15, row = (l>>4)*4 + reg
  int r0 = bm * 128 + w * 32 + (l >> 4) * 4;
  int cb = bn * 64 + (l & 15);
#pragma unroll
  for (int m = 0; m < 2; ++m)
#pragma unroll
    for (int reg = 0; reg < 4; ++reg) {
      float* dst = dot + (size_t)(r0 + m * 16 + reg) * NC + cb;
#pragma unroll
      for (int n = 0; n < 4; ++n) dst[n * 16] = acc[m][n][reg];
    }
}

// ---------------- sum of valid resid norms (from own-cluster dot) ----------------
__global__ __launch_bounds__(256) void k_resid2(const float* __restrict__ dot,
                                                const int* __restrict__ clu,
                                                const float* __restrict__ onorm2,
                                                const float* __restrict__ mnorm2,
                                                const float* __restrict__ counts,
                                                float* scal) {
  __shared__ float part[4];
  int tid = threadIdx.x;
  int i = blockIdx.x * 256 + tid;
  int ci = clu[i];
  float dv = dot[(size_t)i * NC + ci];
  float rn = sqrtf(fmaxf(onorm2[i] - 2.f * dv + mnorm2[ci], 0.f));
  float v = (counts[ci] >= 4.0f) ? rn : 0.f;
  v = wave_red_sum(v);
  if ((tid & 63) == 0) part[tid >> 6] = v;
  __syncthreads();
  if (tid == 0) atomicAdd(&scal[0], part[0] + part[1] + part[2] + part[3]);
}

__global__ void k_stdev(float* scal) {
  scal[2] = scal[0] * scal[0] / scal[1];
}

// ---------------- denom + loss (one wave per instance row) ----------------
__global__ __launch_bounds__(256) void k_denom(const float* __restrict__ dot,
                                               const int* __restrict__ clu,
                                               const float* __restrict__ onorm2,
                                               const float* __restrict__ mnorm2,
                                               const float* __restrict__ counts,
                                               float* scal) {
  int w = threadIdx.x >> 6, l = threadIdx.x & 63;
  int i = blockIdx.x * 4 + w;
  int ci = clu[i];
  float on2 = onorm2[i];
  float cfac = -0.5f / scal[2];
  f32x4 dv = ((const f32x4*)(dot + (size_t)i * NC))[l];
  f32x4 mn = ((const f32x4*)mnorm2)[l];
  f32x4 cn = ((const f32x4*)counts)[l];
  float dsum = 0.f;
#pragma unroll
  for (int j = 0; j < 4; ++j) {
    int c = l * 4 + j;
    float dist = sqrtf(fmaxf(on2 - 2.f * dv[j] + mn[j], 0.f));
    float e = __expf(cfac * dist);
    dsum += ((cn[j] >= 4.0f) && (c != ci)) ? e : 0.f;
  }
  dsum = wave_red_sum(dsum);
  if (l == 0 && counts[ci] >= 4.0f) {
    float dvi = dot[(size_t)i * NC + ci];
    float rn = sqrtf(fmaxf(on2 - 2.f * dvi + mnorm2[ci], 0.f));
    float loss_i = __logf(dsum) - (cfac * rn - ALPHA_C);
    atomicAdd(&scal[3], loss_i);
  }
}

__global__ void k_final(const float* scal, float* out) {
  out[0] = scal[3] / scal[1];
}

extern "C" void kernel_launch(void* const* d_in, const int* in_sizes, int n_in,
                              void* d_out, int out_size, void* d_ws, size_t ws_size,
                              hipStream_t stream) {
  const float* outputs = (const float*)d_in[0];
  const int* clusters = (const int*)d_in[1];
  float* out = (float*)d_out;
  char* ws = (char*)d_ws;

  bf16x8* A      = (bf16x8*)(ws + OFF_A);
  float*  dotb   = (float*)(ws + OFF_DOT);
  float*  ps     = (float*)(ws + OFF_PS);
  bf16x8* B      = (bf16x8*)(ws + OFF_B);
  float*  counts = (float*)(ws + OFF_CNT);
  float*  mn2    = (float*)(ws + OFF_MN2);
  float*  on2    = (float*)(ws + OFF_ON2);
  float*  scal   = (float*)(ws + OFF_SCAL);

  hipMemsetAsync(scal, 0, 64, stream);
  k_counts<<<1, 256, 0, stream>>>(clusters, counts, scal);
  k_sums<<<128, 256, 0, stream>>>(outputs, clusters, ps);
  k_conv<<<NROWS, 256, 0, stream>>>(outputs, A, on2);
  k_means<<<NC, 256, 0, stream>>>(ps, counts, B, mn2);
  k_gemm<<<256, 256, 0, stream>>>(A, B, dotb);
  k_resid2<<<NROWS / 256, 256, 0, stream>>>(dotb, clusters, on2, mn2, counts, scal);
  k_stdev<<<1, 1, 0, stream>>>(scal);
  k_denom<<<NROWS / 4, 256, 0, stream>>>(dotb, clusters, on2, mn2, counts, scal);
  k_final<<<1, 1, 0, stream>>>(scal, out);
}

// Round 3
// 197.958 us; speedup vs baseline: 2.4952x; 2.4952x over previous
//
#include <hip/hip_runtime.h>
#include <hip/hip_bf16.h>
#include <math.h>

#define NROWS 8192
#define DIM   2048
#define NC    256
#define ALPHA_C 7.18f

typedef float  f32x4  __attribute__((ext_vector_type(4)));
typedef __bf16 bf16x8 __attribute__((ext_vector_type(8)));

// ---------------- workspace layout (bytes) ----------------
// A_swz : 32 MiB  bf16 [512 mt][64 kk][64 lane][8]
// dot   :  8 MiB  f32  [8192][256]
// B_swz :  1 MiB  bf16 [16 nt][64 kk][64 lane][8]
// perm  : 32 KiB  int[8192]  rows grouped by cluster
// misc  : gctr[256] | mnorm2[256] | scal[16] (these 3 KiB memset to 0)
//         counts[256] | base[256] | onorm2[8192]
#define OFF_A      (size_t)0
#define OFF_DOT    ((size_t)32 << 20)
#define OFF_B      ((size_t)40 << 20)
#define OFF_PERM   ((size_t)41 << 20)
#define OFF_MISC   (OFF_PERM + 32768)
#define OFF_GCTR   (OFF_MISC)
#define OFF_MN2    (OFF_MISC + 1024)
#define OFF_SCAL   (OFF_MISC + 2048)
#define OFF_CNT    (OFF_MISC + 3072)
#define OFF_BASE   (OFF_MISC + 4096)
#define OFF_ON2    (OFF_MISC + 5120)
// scal: [0]=sum_resid(atomic) [1]=num_instances [2]=stdev [3]=loss_sum(atomic)

__device__ __forceinline__ float wave_red_sum(float v) {
#pragma unroll
  for (int off = 32; off > 0; off >>= 1) v += __shfl_xor(v, off, 64);
  return v;
}

// ---------------- counts + exclusive prefix + num_instances ----------------
__global__ __launch_bounds__(256) void k_counts(const int* __restrict__ clu,
                                                float* __restrict__ counts,
                                                int* __restrict__ base,
                                                float* scal) {
  __shared__ int cnt[NC];
  __shared__ int pre[NC];
  __shared__ float part[4];
  int tid = threadIdx.x;
  cnt[tid] = 0;
  __syncthreads();
  for (int i = tid; i < NROWS; i += 256) atomicAdd(&cnt[clu[i]], 1);
  __syncthreads();
  int c = cnt[tid];
  counts[tid] = (float)c;
  pre[tid] = c;
  __syncthreads();
  for (int off = 1; off < NC; off <<= 1) {
    int v = (tid >= off) ? pre[tid - off] : 0;
    __syncthreads();
    pre[tid] += v;
    __syncthreads();
  }
  base[tid] = pre[tid] - c;  // exclusive prefix
  float v = (c >= 4) ? (float)c : 0.0f;
  v = wave_red_sum(v);
  if ((tid & 63) == 0) part[tid >> 6] = v;
  __syncthreads();
  if (tid == 0) scal[1] = part[0] + part[1] + part[2] + part[3];
}

// ---------------- build permutation grouping rows by cluster ----------------
__global__ __launch_bounds__(256) void k_perm(const int* __restrict__ clu,
                                              const int* __restrict__ base,
                                              int* __restrict__ gctr,
                                              int* __restrict__ perm) {
  int i = blockIdx.x * 256 + threadIdx.x;
  int c = clu[i];
  int r = atomicAdd(&gctr[c], 1);
  perm[base[c] + r] = i;
}

// ---------------- means via gather-reduce over sorted rows ----------------
// grid 2048 = 256 clusters x 8 column-slices (256 cols each)
__global__ __launch_bounds__(256) void k_msum(const float* __restrict__ out,
                                              const int* __restrict__ perm,
                                              const int* __restrict__ base,
                                              const float* __restrict__ counts,
                                              __bf16* __restrict__ B,
                                              float* __restrict__ mn2) {
  __shared__ int pr[64];
  __shared__ float part[4];
  int bid = blockIdx.x;
  int c = bid >> 3, sl = bid & 7;
  int tid = threadIdx.x;
  int col = sl * 256 + tid;
  int cnt = (int)counts[c];
  int b0 = base[c];
  float acc = 0.f;
  for (int r0 = 0; r0 < cnt; r0 += 64) {
    int lim = min(64, cnt - r0);
    if (tid < lim) pr[tid] = perm[b0 + r0 + tid];
    __syncthreads();
    for (int r = 0; r < lim; ++r) acc += out[(size_t)pr[r] * DIM + col];
    __syncthreads();
  }
  float mean = acc / fmaxf((float)cnt, 1.f);
  // bf16 B fragment (same layout as GEMM expects): k index = col, n index = c
  int nt = c >> 4, kk = col >> 5, lane = ((col >> 3) & 3) * 16 + (c & 15), j = col & 7;
  B[(((size_t)nt * 64 + kk) * 64 + lane) * 8 + j] = (__bf16)mean;
  float s = mean * mean;
  s = wave_red_sum(s);
  if ((tid & 63) == 0) part[tid >> 6] = s;
  __syncthreads();
  if (tid == 0) atomicAdd(&mn2[c], part[0] + part[1] + part[2] + part[3]);
}

// ---------------- convert outputs -> A_swz (bf16 fragment layout) + onorm2 ----------------
__global__ __launch_bounds__(256) void k_conv(const float* __restrict__ out,
                                              bf16x8* __restrict__ A,
                                              float* __restrict__ onorm2) {
  __shared__ float part[4];
  int r = blockIdx.x, tid = threadIdx.x;
  const f32x4* src = (const f32x4*)(out + (size_t)r * DIM);
  f32x4 v0 = src[tid * 2], v1 = src[tid * 2 + 1];
  float s = 0.f;
  bf16x8 b;
#pragma unroll
  for (int j = 0; j < 4; ++j) { float f = v0[j]; s += f * f; b[j] = (__bf16)f; }
#pragma unroll
  for (int j = 0; j < 4; ++j) { float f = v1[j]; s += f * f; b[4 + j] = (__bf16)f; }
  int mt = r >> 4, kk = tid >> 2, lane = (tid & 3) * 16 + (r & 15);
  A[((size_t)mt * 64 + kk) * 64 + lane] = b;
  s = wave_red_sum(s);
  if ((tid & 63) == 0) part[tid >> 6] = s;
  __syncthreads();
  if (tid == 0) onorm2[r] = part[0] + part[1] + part[2] + part[3];
}

// ---------------- GEMM: dot[i][c] = outputs_i . mean_c (bf16 MFMA) ----------------
__global__ __launch_bounds__(256) void k_gemm(const bf16x8* __restrict__ A,
                                              const bf16x8* __restrict__ B,
                                              float* __restrict__ dot) {
  int bid = blockIdx.x;
  int wg = (bid & 7) * 32 + (bid >> 3);   // bijective: 256 = 8 XCD x 32
  int bm = wg >> 2, bn = wg & 3;
  int w = threadIdx.x >> 6, l = threadIdx.x & 63;
  int mt0 = bm * 8 + w * 2;
  int nt0 = bn * 4;
  const bf16x8* Ap = A + (size_t)mt0 * 64 * 64 + l;
  const bf16x8* Bp = B + (size_t)nt0 * 64 * 64 + l;
  f32x4 acc[2][4] = {};
  for (int kk = 0; kk < 64; ++kk) {
    bf16x8 a0 = Ap[kk * 64];
    bf16x8 a1 = Ap[4096 + kk * 64];
    bf16x8 b0 = Bp[kk * 64];
    bf16x8 b1 = Bp[4096 + kk * 64];
    bf16x8 b2 = Bp[8192 + kk * 64];
    bf16x8 b3 = Bp[12288 + kk * 64];
    acc[0][0] = __builtin_amdgcn_mfma_f32_16x16x32_bf16(a0, b0, acc[0][0], 0, 0, 0);
    acc[0][1] = __builtin_amdgcn_mfma_f32_16x16x32_bf16(a0, b1, acc[0][1], 0, 0, 0);
    acc[0][2] = __builtin_amdgcn_mfma_f32_16x16x32_bf16(a0, b2, acc[0][2], 0, 0, 0);
    acc[0][3] = __builtin_amdgcn_mfma_f32_16x16x32_bf16(a0, b3, acc[0][3], 0, 0, 0);
    acc[1][0] = __builtin_amdgcn_mfma_f32_16x16x32_bf16(a1, b0, acc[1][0], 0, 0, 0);
    acc[1][1] = __builtin_amdgcn_mfma_f32_16x16x32_bf16(a1, b1, acc[1][1], 0, 0, 0);
    acc[1][2] = __builtin_amdgcn_mfma_f32_16x16x32_bf16(a1, b2, acc[1][2], 0, 0, 0);
    acc[1][3] = __builtin_amdgcn_mfma_f32_16x16x32_bf16(a1, b3, acc[1][3], 0, 0, 0);
  }
  // C/D layout (m89-verified): col = l&15, row = (l>>4)*4 + reg
  int r0 = bm * 128 + w * 32 + (l >> 4) * 4;
  int cb = bn * 64 + (l & 15);
#pragma unroll
  for (int m = 0; m < 2; ++m)
#pragma unroll
    for (int reg = 0; reg < 4; ++reg) {
      float* dst = dot + (size_t)(r0 + m * 16 + reg) * NC + cb;
#pragma unroll
      for (int n = 0; n < 4; ++n) dst[n * 16] = acc[m][n][reg];
    }
}

// ---------------- sum of valid resid norms (from own-cluster dot) ----------------
__global__ __launch_bounds__(256) void k_resid2(const float* __restrict__ dot,
                                                const int* __restrict__ clu,
                                                const float* __restrict__ onorm2,
                                                const float* __restrict__ mnorm2,
                                                const float* __restrict__ counts,
                                                float* scal) {
  __shared__ float part[4];
  int tid = threadIdx.x;
  int i = blockIdx.x * 256 + tid;
  int ci = clu[i];
  float dv = dot[(size_t)i * NC + ci];
  float rn = sqrtf(fmaxf(onorm2[i] - 2.f * dv + mnorm2[ci], 0.f));
  float v = (counts[ci] >= 4.0f) ? rn : 0.f;
  v = wave_red_sum(v);
  if ((tid & 63) == 0) part[tid >> 6] = v;
  __syncthreads();
  if (tid == 0) atomicAdd(&scal[0], part[0] + part[1] + part[2] + part[3]);
}

__global__ void k_stdev(float* scal) {
  scal[2] = scal[0] * scal[0] / scal[1];
}

// ---------------- denom + loss: 256 blocks x 32 rows, 1 atomic per block ----------------
__global__ __launch_bounds__(256) void k_denom(const float* __restrict__ dot,
                                               const int* __restrict__ clu,
                                               const float* __restrict__ on2v,
                                               const float* __restrict__ mn2,
                                               const float* __restrict__ counts,
                                               float* scal) {
  __shared__ float part[4];
  int w = threadIdx.x >> 6, l = threadIdx.x & 63;
  float cfac = -0.5f / scal[2];
  f32x4 mn = ((const f32x4*)mn2)[l];
  f32x4 cn = ((const f32x4*)counts)[l];
  float lsum = 0.f;
  int i0 = blockIdx.x * 32 + w * 8;
  for (int t = 0; t < 8; ++t) {
    int i = i0 + t;
    int ci = clu[i];
    float on2 = on2v[i];
    f32x4 dv = ((const f32x4*)(dot + (size_t)i * NC))[l];
    float dsum = 0.f;
#pragma unroll
    for (int j = 0; j < 4; ++j) {
      int cc = l * 4 + j;
      float dist = sqrtf(fmaxf(on2 - 2.f * dv[j] + mn[j], 0.f));
      float e = __expf(cfac * dist);
      dsum += ((cn[j] >= 4.0f) && (cc != ci)) ? e : 0.f;
    }
    dsum = wave_red_sum(dsum);
    if (l == 0 && counts[ci] >= 4.0f) {
      float dvi = dot[(size_t)i * NC + ci];
      float rn = sqrtf(fmaxf(on2 - 2.f * dvi + mn2[ci], 0.f));
      lsum += __logf(dsum) - (cfac * rn - ALPHA_C);
    }
  }
  lsum = wave_red_sum(lsum);  // only lane 0 contributed; broadcast-sum
  if (l == 0) part[w] = lsum;
  __syncthreads();
  if (threadIdx.x == 0) atomicAdd(&scal[3], part[0] + part[1] + part[2] + part[3]);
}

__global__ void k_final(const float* scal, float* out) {
  out[0] = scal[3] / scal[1];
}

extern "C" void kernel_launch(void* const* d_in, const int* in_sizes, int n_in,
                              void* d_out, int out_size, void* d_ws, size_t ws_size,
                              hipStream_t stream) {
  const float* outputs = (const float*)d_in[0];
  const int* clusters = (const int*)d_in[1];
  float* out = (float*)d_out;
  char* ws = (char*)d_ws;

  bf16x8* A      = (bf16x8*)(ws + OFF_A);
  float*  dotb   = (float*)(ws + OFF_DOT);
  __bf16* B      = (__bf16*)(ws + OFF_B);
  int*    perm   = (int*)(ws + OFF_PERM);
  int*    gctr   = (int*)(ws + OFF_GCTR);
  float*  mn2    = (float*)(ws + OFF_MN2);
  float*  scal   = (float*)(ws + OFF_SCAL);
  float*  counts = (float*)(ws + OFF_CNT);
  int*    base   = (int*)(ws + OFF_BASE);
  float*  on2    = (float*)(ws + OFF_ON2);

  hipMemsetAsync(ws + OFF_GCTR, 0, 3072, stream);  // gctr, mn2, scal
  k_counts<<<1, 256, 0, stream>>>(clusters, counts, base, scal);
  k_perm<<<NROWS / 256, 256, 0, stream>>>(clusters, base, gctr, perm);
  k_conv<<<NROWS, 256, 0, stream>>>(outputs, A, on2);
  k_msum<<<NC * 8, 256, 0, stream>>>(outputs, perm, base, counts, B, mn2);
  k_gemm<<<256, 256, 0, stream>>>(A, (const bf16x8*)B, dotb);
  k_resid2<<<NROWS / 256, 256, 0, stream>>>(dotb, clusters, on2, mn2, counts, scal);
  k_stdev<<<1, 1, 0, stream>>>(scal);
  k_denom<<<NROWS / 32, 256, 0, stream>>>(dotb, clusters, on2, mn2, counts, scal);
  k_final<<<1, 1, 0, stream>>>(scal, out);
}

// Round 4
// 179.382 us; speedup vs baseline: 2.7536x; 1.1036x over previous
//
#include <hip/hip_runtime.h>
#include <hip/hip_bf16.h>
#include <math.h>

#define NROWS 8192
#define DIM   2048
#define NC    256
#define ALPHA_C 7.18f

typedef float  f32x4  __attribute__((ext_vector_type(4)));
typedef __bf16 bf16x8 __attribute__((ext_vector_type(8)));

// ---------------- workspace layout (bytes) ----------------
// A_swz : 32 MiB  bf16 [512 mt][64 kk][64 lane][8]
// dot   :  8 MiB  f32  [8192][256]
// B_swz :  1 MiB  bf16 [16 nt][64 kk][64 lane][8]
// perm  : 32 KiB  int[8192]  rows grouped by cluster
// misc  : gctr[256] | mnorm2[256] | scal[16] | hist[256]   <- 4 KiB memset to 0
//         counts[256] | base[256] | onorm2[8192]
#define OFF_A      (size_t)0
#define OFF_DOT    ((size_t)32 << 20)
#define OFF_B      ((size_t)40 << 20)
#define OFF_PERM   ((size_t)41 << 20)
#define OFF_MISC   (OFF_PERM + 32768)
#define OFF_GCTR   (OFF_MISC)
#define OFF_MN2    (OFF_MISC + 1024)
#define OFF_SCAL   (OFF_MISC + 2048)
#define OFF_HIST   (OFF_MISC + 3072)
#define OFF_CNT    (OFF_MISC + 4096)
#define OFF_BASE   (OFF_MISC + 5120)
#define OFF_ON2    (OFF_MISC + 6144)
// scal: [0]=sum_resid(atomic) [1]=num_instances [2]=stdev [3]=loss_sum(atomic)

__device__ __forceinline__ float wave_red_sum(float v) {
#pragma unroll
  for (int off = 32; off > 0; off >>= 1) v += __shfl_xor(v, off, 64);
  return v;
}

// ---------------- histogram of cluster ids (32 blocks) ----------------
__global__ __launch_bounds__(256) void k_hist(const int* __restrict__ clu,
                                              int* __restrict__ hist) {
  __shared__ int h[NC];
  int tid = threadIdx.x;
  h[tid] = 0;
  __syncthreads();
  atomicAdd(&h[clu[blockIdx.x * 256 + tid]], 1);
  __syncthreads();
  if (h[tid]) atomicAdd(&hist[tid], h[tid]);
}

// ---------------- prefix + counts + num_instances (1 tiny block) ----------------
__global__ __launch_bounds__(256) void k_scan(const int* __restrict__ hist,
                                              float* __restrict__ counts,
                                              int* __restrict__ base,
                                              float* scal) {
  __shared__ int pre[NC];
  __shared__ float part[4];
  int tid = threadIdx.x;
  int c = hist[tid];
  counts[tid] = (float)c;
  pre[tid] = c;
  __syncthreads();
  for (int off = 1; off < NC; off <<= 1) {
    int v = (tid >= off) ? pre[tid - off] : 0;
    __syncthreads();
    pre[tid] += v;
    __syncthreads();
  }
  base[tid] = pre[tid] - c;  // exclusive prefix
  float v = (c >= 4) ? (float)c : 0.0f;
  v = wave_red_sum(v);
  if ((tid & 63) == 0) part[tid >> 6] = v;
  __syncthreads();
  if (tid == 0) scal[1] = part[0] + part[1] + part[2] + part[3];
}

// ---------------- build permutation grouping rows by cluster ----------------
__global__ __launch_bounds__(256) void k_perm(const int* __restrict__ clu,
                                              const int* __restrict__ base,
                                              int* __restrict__ gctr,
                                              int* __restrict__ perm) {
  int i = blockIdx.x * 256 + threadIdx.x;
  int c = clu[i];
  int r = atomicAdd(&gctr[c], 1);
  perm[base[c] + r] = i;
}

// ---------------- means via gather-reduce over sorted rows ----------------
// grid 2048 = 256 clusters x 8 column-slices (256 cols each)
__global__ __launch_bounds__(256) void k_msum(const float* __restrict__ out,
                                              const int* __restrict__ perm,
                                              const int* __restrict__ base,
                                              const float* __restrict__ counts,
                                              __bf16* __restrict__ B,
                                              float* __restrict__ mn2) {
  __shared__ int pr[64];
  __shared__ float part[4];
  int bid = blockIdx.x;
  int c = bid >> 3, sl = bid & 7;
  int tid = threadIdx.x;
  int col = sl * 256 + tid;
  int cnt = (int)counts[c];
  int b0 = base[c];
  float acc = 0.f;
  for (int r0 = 0; r0 < cnt; r0 += 64) {
    int lim = min(64, cnt - r0);
    if (tid < lim) pr[tid] = perm[b0 + r0 + tid];
    __syncthreads();
    for (int r = 0; r < lim; ++r) acc += out[(size_t)pr[r] * DIM + col];
    __syncthreads();
  }
  float mean = acc / fmaxf((float)cnt, 1.f);
  // bf16 B fragment (same layout as GEMM expects): k index = col, n index = c
  int nt = c >> 4, kk = col >> 5, lane = ((col >> 3) & 3) * 16 + (c & 15), j = col & 7;
  B[(((size_t)nt * 64 + kk) * 64 + lane) * 8 + j] = (__bf16)mean;
  float s = mean * mean;
  s = wave_red_sum(s);
  if ((tid & 63) == 0) part[tid >> 6] = s;
  __syncthreads();
  if (tid == 0) atomicAdd(&mn2[c], part[0] + part[1] + part[2] + part[3]);
}

// ---------------- outputs -> A_swz + onorm2, one block per 16-row M-tile ----------------
// A entry q (0..4095) of tile mt: kk=q>>6, lane=q&63; holds row (mt*16 + (lane&15)),
// cols d = kk*32 + (lane>>4)*8 + 0..7.  Thread tid writes q = s*256+tid (s=0..15):
// every wave-store is 1 KiB contiguous; per-thread row is fixed (= tid&15).
__global__ __launch_bounds__(256) void k_conv(const float* __restrict__ out,
                                              bf16x8* __restrict__ A,
                                              float* __restrict__ onorm2) {
  __shared__ float lsum[256];
  int mt = blockIdx.x, tid = threadIdx.x;
  int r = tid & 15;
  const float* rowp = out + ((size_t)mt * 16 + r) * DIM;
  bf16x8* At = A + (size_t)mt * 4096;
  float acc = 0.f;
#pragma unroll 4
  for (int s = 0; s < 16; ++s) {
    int q = s * 256 + tid;
    int kk = q >> 6, lane = q & 63;
    int d = kk * 32 + (lane >> 4) * 8;
    const f32x4* src = (const f32x4*)(rowp + d);
    f32x4 v0 = src[0], v1 = src[1];
    bf16x8 b;
#pragma unroll
    for (int j = 0; j < 4; ++j) { float f = v0[j]; acc += f * f; b[j] = (__bf16)f; }
#pragma unroll
    for (int j = 0; j < 4; ++j) { float f = v1[j]; acc += f * f; b[4 + j] = (__bf16)f; }
    At[q] = b;
  }
  lsum[tid] = acc;
  __syncthreads();
  if (tid < 16) {
    float s = 0.f;
#pragma unroll
    for (int k = 0; k < 16; ++k) s += lsum[tid + 16 * k];
    onorm2[mt * 16 + tid] = s;
  }
}

// ---------------- GEMM: dot[i][c] = outputs_i . mean_c (bf16 MFMA) ----------------
__global__ __launch_bounds__(256) void k_gemm(const bf16x8* __restrict__ A,
                                              const bf16x8* __restrict__ B,
                                              float* __restrict__ dot) {
  int bid = blockIdx.x;
  int wg = (bid & 7) * 32 + (bid >> 3);   // bijective: 256 = 8 XCD x 32
  int bm = wg >> 2, bn = wg & 3;
  int w = threadIdx.x >> 6, l = threadIdx.x & 63;
  int mt0 = bm * 8 + w * 2;
  int nt0 = bn * 4;
  const bf16x8* Ap = A + (size_t)mt0 * 64 * 64 + l;
  const bf16x8* Bp = B + (size_t)nt0 * 64 * 64 + l;
  f32x4 acc[2][4] = {};
  for (int kk = 0; kk < 64; ++kk) {
    bf16x8 a0 = Ap[kk * 64];
    bf16x8 a1 = Ap[4096 + kk * 64];
    bf16x8 b0 = Bp[kk * 64];
    bf16x8 b1 = Bp[4096 + kk * 64];
    bf16x8 b2 = Bp[8192 + kk * 64];
    bf16x8 b3 = Bp[12288 + kk * 64];
    acc[0][0] = __builtin_amdgcn_mfma_f32_16x16x32_bf16(a0, b0, acc[0][0], 0, 0, 0);
    acc[0][1] = __builtin_amdgcn_mfma_f32_16x16x32_bf16(a0, b1, acc[0][1], 0, 0, 0);
    acc[0][2] = __builtin_amdgcn_mfma_f32_16x16x32_bf16(a0, b2, acc[0][2], 0, 0, 0);
    acc[0][3] = __builtin_amdgcn_mfma_f32_16x16x32_bf16(a0, b3, acc[0][3], 0, 0, 0);
    acc[1][0] = __builtin_amdgcn_mfma_f32_16x16x32_bf16(a1, b0, acc[1][0], 0, 0, 0);
    acc[1][1] = __builtin_amdgcn_mfma_f32_16x16x32_bf16(a1, b1, acc[1][1], 0, 0, 0);
    acc[1][2] = __builtin_amdgcn_mfma_f32_16x16x32_bf16(a1, b2, acc[1][2], 0, 0, 0);
    acc[1][3] = __builtin_amdgcn_mfma_f32_16x16x32_bf16(a1, b3, acc[1][3], 0, 0, 0);
  }
  // C/D layout (m89-verified): col = l&15, row = (l>>4)*4 + reg
  int r0 = bm * 128 + w * 32 + (l >> 4) * 4;
  int cb = bn * 64 + (l & 15);
#pragma unroll
  for (int m = 0; m < 2; ++m)
#pragma unroll
    for (int reg = 0; reg < 4; ++reg) {
      float* dst = dot + (size_t)(r0 + m * 16 + reg) * NC + cb;
#pragma unroll
      for (int n = 0; n < 4; ++n) dst[n * 16] = acc[m][n][reg];
    }
}

// ---------------- sum of valid resid norms (from own-cluster dot) ----------------
__global__ __launch_bounds__(256) void k_resid2(const float* __restrict__ dot,
                                                const int* __restrict__ clu,
                                                const float* __restrict__ onorm2,
                                                const float* __restrict__ mnorm2,
                                                const float* __restrict__ counts,
                                                float* scal) {
  __shared__ float part[4];
  int tid = threadIdx.x;
  int i = blockIdx.x * 256 + tid;
  int ci = clu[i];
  float dv = dot[(size_t)i * NC + ci];
  float rn = sqrtf(fmaxf(onorm2[i] - 2.f * dv + mnorm2[ci], 0.f));
  float v = (counts[ci] >= 4.0f) ? rn : 0.f;
  v = wave_red_sum(v);
  if ((tid & 63) == 0) part[tid >> 6] = v;
  __syncthreads();
  if (tid == 0) atomicAdd(&scal[0], part[0] + part[1] + part[2] + part[3]);
}

__global__ void k_stdev(float* scal) {
  scal[2] = scal[0] * scal[0] / scal[1];
}

// ---------------- denom + loss: 256 blocks x 32 rows, 1 atomic per block ----------------
__global__ __launch_bounds__(256) void k_denom(const float* __restrict__ dot,
                                               const int* __restrict__ clu,
                                               const float* __restrict__ on2v,
                                               const float* __restrict__ mn2,
                                               const float* __restrict__ counts,
                                               float* scal) {
  __shared__ float part[4];
  int w = threadIdx.x >> 6, l = threadIdx.x & 63;
  float cfac = -0.5f / scal[2];
  f32x4 mn = ((const f32x4*)mn2)[l];
  f32x4 cn = ((const f32x4*)counts)[l];
  float lsum = 0.f;
  int i0 = blockIdx.x * 32 + w * 8;
  for (int t = 0; t < 8; ++t) {
    int i = i0 + t;
    int ci = clu[i];
    float on2 = on2v[i];
    f32x4 dv = ((const f32x4*)(dot + (size_t)i * NC))[l];
    float dsum = 0.f;
#pragma unroll
    for (int j = 0; j < 4; ++j) {
      int cc = l * 4 + j;
      float dist = sqrtf(fmaxf(on2 - 2.f * dv[j] + mn[j], 0.f));
      float e = __expf(cfac * dist);
      dsum += ((cn[j] >= 4.0f) && (cc != ci)) ? e : 0.f;
    }
    dsum = wave_red_sum(dsum);
    if (l == 0 && counts[ci] >= 4.0f) {
      float dvi = dot[(size_t)i * NC + ci];
      float rn = sqrtf(fmaxf(on2 - 2.f * dvi + mn2[ci], 0.f));
      lsum += __logf(dsum) - (cfac * rn - ALPHA_C);
    }
  }
  lsum = wave_red_sum(lsum);  // only lane 0 contributed; broadcast-sum
  if (l == 0) part[w] = lsum;
  __syncthreads();
  if (threadIdx.x == 0) atomicAdd(&scal[3], part[0] + part[1] + part[2] + part[3]);
}

__global__ void k_final(const float* scal, float* out) {
  out[0] = scal[3] / scal[1];
}

extern "C" void kernel_launch(void* const* d_in, const int* in_sizes, int n_in,
                              void* d_out, int out_size, void* d_ws, size_t ws_size,
                              hipStream_t stream) {
  const float* outputs = (const float*)d_in[0];
  const int* clusters = (const int*)d_in[1];
  float* out = (float*)d_out;
  char* ws = (char*)d_ws;

  bf16x8* A      = (bf16x8*)(ws + OFF_A);
  float*  dotb   = (float*)(ws + OFF_DOT);
  __bf16* B      = (__bf16*)(ws + OFF_B);
  int*    perm   = (int*)(ws + OFF_PERM);
  int*    gctr   = (int*)(ws + OFF_GCTR);
  float*  mn2    = (float*)(ws + OFF_MN2);
  float*  scal   = (float*)(ws + OFF_SCAL);
  int*    hist   = (int*)(ws + OFF_HIST);
  float*  counts = (float*)(ws + OFF_CNT);
  int*    base   = (int*)(ws + OFF_BASE);
  float*  on2    = (float*)(ws + OFF_ON2);

  hipMemsetAsync(ws + OFF_GCTR, 0, 4096, stream);  // gctr, mn2, scal, hist
  k_hist<<<NROWS / 256, 256, 0, stream>>>(clusters, hist);
  k_scan<<<1, 256, 0, stream>>>(hist, counts, base, scal);
  k_perm<<<NROWS / 256, 256, 0, stream>>>(clusters, base, gctr, perm);
  k_conv<<<NROWS / 16, 256, 0, stream>>>(outputs, A, on2);
  k_msum<<<NC * 8, 256, 0, stream>>>(outputs, perm, base, counts, B, mn2);
  k_gemm<<<256, 256, 0, stream>>>(A, (const bf16x8*)B, dotb);
  k_resid2<<<NROWS / 256, 256, 0, stream>>>(dotb, clusters, on2, mn2, counts, scal);
  k_stdev<<<1, 1, 0, stream>>>(scal);
  k_denom<<<NROWS / 32, 256, 0, stream>>>(dotb, clusters, on2, mn2, counts, scal);
  k_final<<<1, 1, 0, stream>>>(scal, out);
}